// Round 12
// baseline (182.056 us; speedup 1.0000x reference)
//
#include <hip/hip_runtime.h>
#include <math.h>

namespace {

constexpr int H = 1024;
constexpr int W = 1024;
constexpr int HW = H * W;
constexpr int TILE = 64;             // output tile edge
constexpr int HALO = 32;             // = steps fused per launch
constexpr int P = 128;               // halo'd tile edge = TILE + 2*HALO
constexpr int TSTEP = 32;            // steps per launch
constexpr int NLAUNCH = 2;           // 2 x 32 = 64 steps
constexpr int NTX = W / TILE;        // 16 tiles per dim
constexpr int NTHREADS = 512;        // 8 waves; VGPR cap 256 -> spill-safe
constexpr int NWAVES = 8;
constexpr int RPW = P / NWAVES;      // 16 rows per wave; lane owns 16 rows x 2 cols

typedef float f2 __attribute__((ext_vector_type(2)));

__device__ __forceinline__ float clampf(float v, float lo, float hi) {
    return fminf(fmaxf(v, lo), hi);            // -> v_med3_f32
}
__device__ __forceinline__ f2 clamp2(f2 v, float lo, float hi) {
    f2 r;
    r.x = clampf(v.x, lo, hi);
    r.y = clampf(v.y, lo, hi);
    return r;
}
// DPP wave shifts (gfx9-lineage, CDNA keeps them). row_shr semantics: lane i
// gets lane i-N. wave_shr:1 (0x138) -> value from lane-1 (left neighbor);
// wave_shl:1 (0x130) -> value from lane+1 (right neighbor). bound_ctrl=false:
// boundary lanes keep their own value -> feeds only garbage-ring columns.
__device__ __forceinline__ float dpp_left(float x) {
    int r = __builtin_amdgcn_update_dpp(__float_as_int(x), __float_as_int(x),
                                        0x138, 0xF, 0xF, false);
    return __int_as_float(r);
}
__device__ __forceinline__ float dpp_right(float x) {
    int r = __builtin_amdgcn_update_dpp(__float_as_int(x), __float_as_int(x),
                                        0x130, 0xF, 0xF, false);
    return __int_as_float(r);
}

// 32 fused Gray-Scott steps on a 64x64 tile, halo 32, STATE IN REGISTERS.
// Lane owns 16 rows x 2 cols x 2 fields (64 VGPRs). Horizontal neighbors via
// DPP wave-shift (VALU); vertical neighbors in-register; only wave-boundary
// rows go through a tiny double-buffered LDS halo (1 barrier/step). Step s
// computes rows [s,127-s] at wave granularity; everything outside is
// clamped-finite garbage that the valid region never reads (region shrinks
// monotonically, so inactive waves stay inactive and their stale halos feed
// only garbage rows).
__global__ __launch_bounds__(NTHREADS) void gs_reg(
    const float* __restrict__ Uin, const float* __restrict__ Vin,
    float* __restrict__ Uout, float* __restrict__ Vout,
    const float* __restrict__ pLogDu, const float* __restrict__ pLogDv,
    const float* __restrict__ pf, const float* __restrict__ pk_,
    float ix2, float iy2, float dt)
{
    __shared__ __align__(16) float halo[2][NWAVES][2][2][P];  // 32 KB

    const int tid = threadIdx.x;
    const int w = tid >> 6;          // wave 0..7
    const int l = tid & 63;          // lane
    const int bx = blockIdx.x & (NTX - 1);
    const int by = blockIdx.x >> 4;
    const int gx = (bx * TILE - HALO + 2 * l) & (W - 1);   // even; no mid-pair wrap
    const int r0g = by * TILE - HALO + RPW * w;            // global row of reg-row 0
    const int wrow = RPW * w;                              // tile-local first row

    const float Du = clampf(expf(pLogDu[0]), 0.001f, 1.0f);
    const float Dv = clampf(expf(pLogDv[0]), 0.001f, 1.0f);
    const float f = pf[0];
    const float fk = pf[0] + pk_[0];

    // ---- load state: 16 rows x 2 cols per field, periodic wrap ----
    // No leading clamp: inputs are in [0,2] by construction (identity clip).
    f2 u[RPW], v[RPW];
#pragma unroll
    for (int r = 0; r < RPW; ++r) {
        const int gy = (r0g + r) & (H - 1);
        u[r] = *reinterpret_cast<const f2*>(Uin + gy * W + gx);
        v[r] = *reinterpret_cast<const f2*>(Vin + gy * W + gx);
    }

    for (int s = 1; s <= TSTEP; ++s) {
        const int p = s & 1;
        // publish boundary rows (all waves; stale values only ever feed
        // garbage rows -- see activity analysis)
        *reinterpret_cast<f2*>(&halo[p][w][0][0][2 * l]) = u[0];
        *reinterpret_cast<f2*>(&halo[p][w][0][1][2 * l]) = v[0];
        *reinterpret_cast<f2*>(&halo[p][w][1][0][2 * l]) = u[RPW - 1];
        *reinterpret_cast<f2*>(&halo[p][w][1][1][2 * l]) = v[RPW - 1];
        __syncthreads();

        const bool active = (wrow <= (P - 1) - s) && (wrow + RPW - 1 >= s);
        if (active) {
            const int wn = (w > 0) ? w - 1 : 0;            // clamped: garbage-ring only
            const int ws_ = (w < NWAVES - 1) ? w + 1 : NWAVES - 1;
            const f2 nU = *reinterpret_cast<const f2*>(&halo[p][wn][1][0][2 * l]);
            const f2 nV = *reinterpret_cast<const f2*>(&halo[p][wn][1][1][2 * l]);
            const f2 sU = *reinterpret_cast<const f2*>(&halo[p][ws_][0][0][2 * l]);
            const f2 sV = *reinterpret_cast<const f2*>(&halo[p][ws_][0][1][2 * l]);

            f2 pu = nU, pv = nV;                           // old row above
#pragma unroll
            for (int r = 0; r < RPW; ++r) {
                const f2 cu = u[r], cv = v[r];
                const f2 bu = (r < RPW - 1) ? u[r + 1] : sU;   // old row below
                const f2 bv = (r < RPW - 1) ? v[r + 1] : sV;

                // horizontal neighbors: cross-lane for outer cols, in-register
                // for the inner pair
                const float lux = dpp_left(cu.y), rux = dpp_right(cu.x);
                const float lvx = dpp_left(cv.y), rvx = dpp_right(cv.x);
                f2 hu, hv;                                  // left+right sums
                hu.x = lux + cu.y;  hu.y = cu.x + rux;
                hv.x = lvx + cv.y;  hv.y = cv.x + rvx;

                f2 lu = (hu - 2.0f * cu) * ix2 + (pu + bu - 2.0f * cu) * iy2;
                f2 lv = (hv - 2.0f * cv) * ix2 + (pv + bv - 2.0f * cv) * iy2;
                lu = clamp2(lu, -10.0f, 10.0f);
                lv = clamp2(lv, -10.0f, 10.0f);

                const f2 uvv = cu * cv * cv;
                const f2 du = clamp2(Du * lu - uvv + f * (1.0f - cu), -1.0f, 1.0f);
                const f2 dv = clamp2(Dv * lv + uvv - fk * cv, -1.0f, 1.0f);
                u[r] = clamp2(cu + du * dt, 0.0f, 2.0f);
                v[r] = clamp2(cv + dv * dt, 0.0f, 2.0f);

                pu = cu; pv = cv;                           // roll down
            }
        }
    }

    // ---- store interior [32,95]^2 = waves 2..5, lanes 16..47, all 16 rows ----
    if (w >= 2 && w <= 5 && l >= 16 && l < 48) {
        const int orow = by * TILE + wrow - HALO;
        const int ocol = bx * TILE + 2 * l - HALO;
#pragma unroll
        for (int r = 0; r < RPW; ++r) {
            *reinterpret_cast<f2*>(Uout + (orow + r) * W + ocol) = u[r];
            *reinterpret_cast<f2*>(Vout + (orow + r) * W + ocol) = v[r];
        }
    }
}

} // namespace

extern "C" void kernel_launch(void* const* d_in, const int* in_sizes, int n_in,
                              void* d_out, int out_size, void* d_ws, size_t ws_size,
                              hipStream_t stream) {
    const float* U0     = (const float*)d_in[0];
    const float* V0     = (const float*)d_in[1];
    const float* pLogDu = (const float*)d_in[2];
    const float* pLogDv = (const float*)d_in[3];
    const float* pf     = (const float*)d_in[4];
    const float* pk     = (const float*)d_in[5];
    // d_in[6] = steps (int32) — fixed at 64 by the problem definition.

    float* wsU  = (float*)d_ws;   // 4 MB
    float* wsV  = wsU + HW;       // 4 MB
    float* outU = (float*)d_out;  // output layout: [U (HW) | V (HW)]
    float* outV = outU + HW;

    const double dx  = 1.0 / (W - 1);
    const double dy  = 1.0 / (H - 1);
    const double dx2 = dx * dx;
    const double dy2 = dy * dy;
    const float invdx2 = (float)(1.0 / dx2);
    const float invdy2 = (float)(1.0 / dy2);
    const float dtf    = (float)(0.1 * ((dx2 < dy2) ? dx2 : dy2) / (4.0 * 0.16));

    const int grid = (H / TILE) * (W / TILE);   // 256 blocks = 1 per CU

    // 2 launches of 32 fused steps: in -> ws -> out.
    gs_reg<<<grid, NTHREADS, 0, stream>>>(U0, V0, wsU, wsV,
                                          pLogDu, pLogDv, pf, pk,
                                          invdx2, invdy2, dtf);
    gs_reg<<<grid, NTHREADS, 0, stream>>>(wsU, wsV, outU, outV,
                                          pLogDu, pLogDv, pf, pk,
                                          invdx2, invdy2, dtf);
}

// Round 13
// 156.326 us; speedup vs baseline: 1.1646x; 1.1646x over previous
//
#include <hip/hip_runtime.h>
#include <math.h>

namespace {

constexpr int H = 1024;
constexpr int W = 1024;
constexpr int HW = H * W;
constexpr int TILE = 64;             // output tile edge
constexpr int HALO = 32;             // = steps fused per launch
constexpr int P = 128;               // halo'd tile edge = TILE + 2*HALO
constexpr int TSTEP = 32;            // steps per launch
constexpr int NTX = W / TILE;        // 16 tiles per dim
constexpr int NTHREADS = 1024;       // 16 waves = 4/SIMD native
constexpr int NWAVES = 16;
constexpr int RPW = P / NWAVES;      // 8 rows per wave; lane owns 8 rows x 2 cols
                                     // -> 32 state VGPRs (+temps ~50) < 128 cap

typedef float f2 __attribute__((ext_vector_type(2)));

__device__ __forceinline__ float clampf(float v, float lo, float hi) {
    return fminf(fmaxf(v, lo), hi);            // -> v_med3_f32
}
__device__ __forceinline__ f2 clamp2(f2 v, float lo, float hi) {
    f2 r;
    r.x = clampf(v.x, lo, hi);
    r.y = clampf(v.y, lo, hi);
    return r;
}
// DPP wave shifts (validated for correctness in R12): 0x138 -> value from
// lane-1 (left neighbor), 0x130 -> value from lane+1 (right neighbor).
// bound_ctrl=false: boundary lanes keep their own value -> feeds only
// garbage-ring columns (col 0 / col 127), outside the valid region.
__device__ __forceinline__ float dpp_left(float x) {
    int r = __builtin_amdgcn_update_dpp(__float_as_int(x), __float_as_int(x),
                                        0x138, 0xF, 0xF, false);
    return __int_as_float(r);
}
__device__ __forceinline__ float dpp_right(float x) {
    int r = __builtin_amdgcn_update_dpp(__float_as_int(x), __float_as_int(x),
                                        0x130, 0xF, 0xF, false);
    return __int_as_float(r);
}

// 32 fused Gray-Scott steps on a 64x64 tile, halo 32, STATE IN REGISTERS.
// R12 lesson: without an explicit occupancy bound the allocator targeted
// 8 waves/SIMD (60 VGPRs) and spilled the whole state. Here: 16 waves x
// __launch_bounds__(1024,4) -> 128-VGPR cap; lane owns 8 rows x 2 cols x 2
// fields = 32 state VGPRs. Horizontal neighbors via DPP (VALU pipe);
// vertical in-register; wave-boundary rows through a 64 KB double-buffered
// LDS halo (1 barrier/step). Step s computes rows [s,127-s] at wave
// granularity; everything outside is clamped-finite garbage never read by
// the valid region (monotone shrink).
__global__ __launch_bounds__(NTHREADS, 4) void gs_reg(
    const float* __restrict__ Uin, const float* __restrict__ Vin,
    float* __restrict__ Uout, float* __restrict__ Vout,
    const float* __restrict__ pLogDu, const float* __restrict__ pLogDv,
    const float* __restrict__ pf, const float* __restrict__ pk_,
    float ix2, float iy2, float dt)
{
    __shared__ __align__(16) float halo[2][NWAVES][2][2][P];  // 64 KB

    const int tid = threadIdx.x;
    const int w = tid >> 6;          // wave 0..15
    const int l = tid & 63;          // lane
    const int bx = blockIdx.x & (NTX - 1);
    const int by = blockIdx.x >> 4;
    const int gx = (bx * TILE - HALO + 2 * l) & (W - 1);   // even; no mid-pair wrap
    const int r0g = by * TILE - HALO + RPW * w;            // global row of reg-row 0
    const int wrow = RPW * w;                              // tile-local first row

    const float Du = clampf(expf(pLogDu[0]), 0.001f, 1.0f);
    const float Dv = clampf(expf(pLogDv[0]), 0.001f, 1.0f);
    const float f = pf[0];
    const float fk = pf[0] + pk_[0];

    // ---- load state: 8 rows x 2 cols per field, periodic wrap ----
    // No leading clamp: inputs are in [0,2] by construction (identity clip).
    f2 u[RPW], v[RPW];
#pragma unroll
    for (int r = 0; r < RPW; ++r) {
        const int gy = (r0g + r) & (H - 1);
        u[r] = *reinterpret_cast<const f2*>(Uin + gy * W + gx);
        v[r] = *reinterpret_cast<const f2*>(Vin + gy * W + gx);
    }

    for (int s = 1; s <= TSTEP; ++s) {
        const int p = s & 1;
        // publish boundary rows (stale values only ever feed garbage rows)
        *reinterpret_cast<f2*>(&halo[p][w][0][0][2 * l]) = u[0];
        *reinterpret_cast<f2*>(&halo[p][w][0][1][2 * l]) = v[0];
        *reinterpret_cast<f2*>(&halo[p][w][1][0][2 * l]) = u[RPW - 1];
        *reinterpret_cast<f2*>(&halo[p][w][1][1][2 * l]) = v[RPW - 1];
        __syncthreads();

        const bool active = (wrow <= (P - 1) - s) && (wrow + RPW - 1 >= s);
        if (active) {
            const int wn = (w > 0) ? w - 1 : 0;            // clamped: garbage-ring only
            const int ws_ = (w < NWAVES - 1) ? w + 1 : NWAVES - 1;
            const f2 nU = *reinterpret_cast<const f2*>(&halo[p][wn][1][0][2 * l]);
            const f2 nV = *reinterpret_cast<const f2*>(&halo[p][wn][1][1][2 * l]);
            const f2 sU = *reinterpret_cast<const f2*>(&halo[p][ws_][0][0][2 * l]);
            const f2 sV = *reinterpret_cast<const f2*>(&halo[p][ws_][0][1][2 * l]);

            f2 pu = nU, pv = nV;                           // old row above
#pragma unroll
            for (int r = 0; r < RPW; ++r) {
                const f2 cu = u[r], cv = v[r];
                const f2 bu = (r < RPW - 1) ? u[r + 1] : sU;   // old row below
                const f2 bv = (r < RPW - 1) ? v[r + 1] : sV;

                // horizontal neighbors: cross-lane for outer cols, in-register
                // for the inner pair
                const float lux = dpp_left(cu.y), rux = dpp_right(cu.x);
                const float lvx = dpp_left(cv.y), rvx = dpp_right(cv.x);
                f2 hu, hv;                                  // left+right sums
                hu.x = lux + cu.y;  hu.y = cu.x + rux;
                hv.x = lvx + cv.y;  hv.y = cv.x + rvx;

                f2 lu = (hu - 2.0f * cu) * ix2 + (pu + bu - 2.0f * cu) * iy2;
                f2 lv = (hv - 2.0f * cv) * ix2 + (pv + bv - 2.0f * cv) * iy2;
                lu = clamp2(lu, -10.0f, 10.0f);
                lv = clamp2(lv, -10.0f, 10.0f);

                const f2 uvv = cu * cv * cv;
                const f2 du = clamp2(Du * lu - uvv + f * (1.0f - cu), -1.0f, 1.0f);
                const f2 dv = clamp2(Dv * lv + uvv - fk * cv, -1.0f, 1.0f);
                u[r] = clamp2(cu + du * dt, 0.0f, 2.0f);
                v[r] = clamp2(cv + dv * dt, 0.0f, 2.0f);

                pu = cu; pv = cv;                           // roll down
            }
        }
    }

    // ---- store interior [32,95]^2 = waves 4..11, lanes 16..47, all 8 rows ----
    if (w >= 4 && w <= 11 && l >= 16 && l < 48) {
        const int orow = by * TILE + wrow - HALO;
        const int ocol = bx * TILE + 2 * l - HALO;
#pragma unroll
        for (int r = 0; r < RPW; ++r) {
            *reinterpret_cast<f2*>(Uout + (orow + r) * W + ocol) = u[r];
            *reinterpret_cast<f2*>(Vout + (orow + r) * W + ocol) = v[r];
        }
    }
}

} // namespace

extern "C" void kernel_launch(void* const* d_in, const int* in_sizes, int n_in,
                              void* d_out, int out_size, void* d_ws, size_t ws_size,
                              hipStream_t stream) {
    const float* U0     = (const float*)d_in[0];
    const float* V0     = (const float*)d_in[1];
    const float* pLogDu = (const float*)d_in[2];
    const float* pLogDv = (const float*)d_in[3];
    const float* pf     = (const float*)d_in[4];
    const float* pk     = (const float*)d_in[5];
    // d_in[6] = steps (int32) — fixed at 64 by the problem definition.

    float* wsU  = (float*)d_ws;   // 4 MB
    float* wsV  = wsU + HW;       // 4 MB
    float* outU = (float*)d_out;  // output layout: [U (HW) | V (HW)]
    float* outV = outU + HW;

    const double dx  = 1.0 / (W - 1);
    const double dy  = 1.0 / (H - 1);
    const double dx2 = dx * dx;
    const double dy2 = dy * dy;
    const float invdx2 = (float)(1.0 / dx2);
    const float invdy2 = (float)(1.0 / dy2);
    const float dtf    = (float)(0.1 * ((dx2 < dy2) ? dx2 : dy2) / (4.0 * 0.16));

    const int grid = (H / TILE) * (W / TILE);   // 256 blocks = 1 per CU

    // 2 launches of 32 fused steps: in -> ws -> out.
    gs_reg<<<grid, NTHREADS, 0, stream>>>(U0, V0, wsU, wsV,
                                          pLogDu, pLogDv, pf, pk,
                                          invdx2, invdy2, dtf);
    gs_reg<<<grid, NTHREADS, 0, stream>>>(wsU, wsV, outU, outV,
                                          pLogDu, pLogDv, pf, pk,
                                          invdx2, invdy2, dtf);
}

// Round 14
// 151.423 us; speedup vs baseline: 1.2023x; 1.0324x over previous
//
#include <hip/hip_runtime.h>
#include <math.h>

namespace {

constexpr int H = 1024;
constexpr int W = 1024;
constexpr int HW = H * W;
constexpr int TILE = 64;             // output tile edge
constexpr int HALO = 32;             // = steps fused per launch
constexpr int P = 128;               // halo'd tile edge = TILE + 2*HALO
constexpr int TSTEP = 32;            // steps per launch
constexpr int NTX = W / TILE;        // 16 tiles per dim
constexpr int NTHREADS = 1024;       // 16 waves = 4/SIMD native
constexpr int NWAVES = 16;
constexpr int RPW = P / NWAVES;      // 8 rows per wave; lane owns 8 rows x 2 cols
                                     // -> 32 state VGPRs; budget pinned to 128

typedef float f2 __attribute__((ext_vector_type(2)));

__device__ __forceinline__ float clampf(float v, float lo, float hi) {
    return fminf(fmaxf(v, lo), hi);            // -> v_med3_f32
}
__device__ __forceinline__ f2 clamp2(f2 v, float lo, float hi) {
    f2 r;
    r.x = clampf(v.x, lo, hi);
    r.y = clampf(v.y, lo, hi);
    return r;
}
// DPP wave shifts (correctness validated R12/R13): 0x138 -> value from lane-1
// (left neighbor), 0x130 -> value from lane+1 (right neighbor).
// bound_ctrl=false: boundary lanes keep their own value -> feeds only
// garbage-ring columns (col 0 / col 127), outside the valid region.
__device__ __forceinline__ float dpp_left(float x) {
    int r = __builtin_amdgcn_update_dpp(__float_as_int(x), __float_as_int(x),
                                        0x138, 0xF, 0xF, false);
    return __int_as_float(r);
}
__device__ __forceinline__ float dpp_right(float x) {
    int r = __builtin_amdgcn_update_dpp(__float_as_int(x), __float_as_int(x),
                                        0x130, 0xF, 0xF, false);
    return __int_as_float(r);
}

// 32 fused Gray-Scott steps on a 64x64 tile, halo 32, STATE IN REGISTERS.
// R12/R13 lesson: __launch_bounds__'s 2nd arg is only a MIN waves/EU — the
// allocator still chased higher occupancy (60/44 VGPRs) and shuffled the
// state instead of keeping it resident. amdgpu_waves_per_eu(4,4) pins
// min=max=4 -> hard 128-VGPR budget, state stays in registers.
// DX2==DY2 exactly (square grid, square domain) -> merged 5-point laplacian.
// Horizontal neighbors via DPP; vertical in-register; wave-boundary rows
// through a 64 KB double-buffered LDS halo (1 barrier/step). Step s computes
// rows [s,127-s] at wave granularity; everything outside is clamped-finite
// garbage never read by the valid region (monotone shrink).
__global__ __launch_bounds__(NTHREADS)
__attribute__((amdgpu_waves_per_eu(4, 4))) void gs_reg(
    const float* __restrict__ Uin, const float* __restrict__ Vin,
    float* __restrict__ Uout, float* __restrict__ Vout,
    const float* __restrict__ pLogDu, const float* __restrict__ pLogDv,
    const float* __restrict__ pf, const float* __restrict__ pk_,
    float inv2, float dt)
{
    __shared__ __align__(16) float halo[2][NWAVES][2][2][P];  // 64 KB

    const int tid = threadIdx.x;
    const int w = tid >> 6;          // wave 0..15
    const int l = tid & 63;          // lane
    const int bx = blockIdx.x & (NTX - 1);
    const int by = blockIdx.x >> 4;
    const int gx = (bx * TILE - HALO + 2 * l) & (W - 1);   // even; no mid-pair wrap
    const int r0g = by * TILE - HALO + RPW * w;            // global row of reg-row 0
    const int wrow = RPW * w;                              // tile-local first row

    const float Du = clampf(expf(pLogDu[0]), 0.001f, 1.0f);
    const float Dv = clampf(expf(pLogDv[0]), 0.001f, 1.0f);
    const float f = pf[0];
    const float fk = pf[0] + pk_[0];

    // ---- load state: 8 rows x 2 cols per field, periodic wrap ----
    // No leading clamp: inputs are in [0,2] by construction (identity clip).
    f2 u[RPW], v[RPW];
#pragma unroll
    for (int r = 0; r < RPW; ++r) {
        const int gy = (r0g + r) & (H - 1);
        u[r] = *reinterpret_cast<const f2*>(Uin + gy * W + gx);
        v[r] = *reinterpret_cast<const f2*>(Vin + gy * W + gx);
    }

    for (int s = 1; s <= TSTEP; ++s) {
        const int p = s & 1;
        // publish boundary rows (stale values only ever feed garbage rows)
        *reinterpret_cast<f2*>(&halo[p][w][0][0][2 * l]) = u[0];
        *reinterpret_cast<f2*>(&halo[p][w][0][1][2 * l]) = v[0];
        *reinterpret_cast<f2*>(&halo[p][w][1][0][2 * l]) = u[RPW - 1];
        *reinterpret_cast<f2*>(&halo[p][w][1][1][2 * l]) = v[RPW - 1];
        __syncthreads();

        const bool active = (wrow <= (P - 1) - s) && (wrow + RPW - 1 >= s);
        if (active) {
            const int wn = (w > 0) ? w - 1 : 0;            // clamped: garbage-ring only
            const int ws_ = (w < NWAVES - 1) ? w + 1 : NWAVES - 1;
            const f2 nU = *reinterpret_cast<const f2*>(&halo[p][wn][1][0][2 * l]);
            const f2 nV = *reinterpret_cast<const f2*>(&halo[p][wn][1][1][2 * l]);
            const f2 sU = *reinterpret_cast<const f2*>(&halo[p][ws_][0][0][2 * l]);
            const f2 sV = *reinterpret_cast<const f2*>(&halo[p][ws_][0][1][2 * l]);

            f2 pu = nU, pv = nV;                           // old row above
#pragma unroll
            for (int r = 0; r < RPW; ++r) {
                const f2 cu = u[r], cv = v[r];
                const f2 bu = (r < RPW - 1) ? u[r + 1] : sU;   // old row below
                const f2 bv = (r < RPW - 1) ? v[r + 1] : sV;

                // horizontal neighbor sums: cross-lane for outer cols,
                // in-register for the inner pair
                const float lux = dpp_left(cu.y), rux = dpp_right(cu.x);
                const float lvx = dpp_left(cv.y), rvx = dpp_right(cv.x);
                f2 hu, hv;
                hu.x = lux + cu.y;  hu.y = cu.x + rux;
                hv.x = lvx + cv.y;  hv.y = cv.x + rvx;

                // DX2 == DY2 -> single merged 5-point laplacian
                f2 lu = clamp2((hu + (pu + bu) - 4.0f * cu) * inv2, -10.0f, 10.0f);
                f2 lv = clamp2((hv + (pv + bv) - 4.0f * cv) * inv2, -10.0f, 10.0f);

                const f2 uvv = cu * cv * cv;
                const f2 du = clamp2(Du * lu - uvv + f * (1.0f - cu), -1.0f, 1.0f);
                const f2 dv = clamp2(Dv * lv + uvv - fk * cv, -1.0f, 1.0f);
                u[r] = clamp2(cu + du * dt, 0.0f, 2.0f);
                v[r] = clamp2(cv + dv * dt, 0.0f, 2.0f);

                pu = cu; pv = cv;                           // roll down
            }
        }
    }

    // ---- store interior [32,95]^2 = waves 4..11, lanes 16..47, all 8 rows ----
    if (w >= 4 && w <= 11 && l >= 16 && l < 48) {
        const int orow = by * TILE + wrow - HALO;
        const int ocol = bx * TILE + 2 * l - HALO;
#pragma unroll
        for (int r = 0; r < RPW; ++r) {
            *reinterpret_cast<f2*>(Uout + (orow + r) * W + ocol) = u[r];
            *reinterpret_cast<f2*>(Vout + (orow + r) * W + ocol) = v[r];
        }
    }
}

} // namespace

extern "C" void kernel_launch(void* const* d_in, const int* in_sizes, int n_in,
                              void* d_out, int out_size, void* d_ws, size_t ws_size,
                              hipStream_t stream) {
    const float* U0     = (const float*)d_in[0];
    const float* V0     = (const float*)d_in[1];
    const float* pLogDu = (const float*)d_in[2];
    const float* pLogDv = (const float*)d_in[3];
    const float* pf     = (const float*)d_in[4];
    const float* pk     = (const float*)d_in[5];
    // d_in[6] = steps (int32) — fixed at 64 by the problem definition.

    float* wsU  = (float*)d_ws;   // 4 MB
    float* wsV  = wsU + HW;       // 4 MB
    float* outU = (float*)d_out;  // output layout: [U (HW) | V (HW)]
    float* outV = outU + HW;

    const double dx  = 1.0 / (W - 1);
    const double dx2 = dx * dx;                 // == dy2 exactly (square grid)
    const float inv2 = (float)(1.0 / dx2);
    const float dtf  = (float)(0.1 * dx2 / (4.0 * 0.16));

    const int grid = (H / TILE) * (W / TILE);   // 256 blocks = 1 per CU

    // 2 launches of 32 fused steps: in -> ws -> out.
    gs_reg<<<grid, NTHREADS, 0, stream>>>(U0, V0, wsU, wsV,
                                          pLogDu, pLogDv, pf, pk,
                                          inv2, dtf);
    gs_reg<<<grid, NTHREADS, 0, stream>>>(wsU, wsV, outU, outV,
                                          pLogDu, pLogDv, pf, pk,
                                          inv2, dtf);
}

// Round 15
// 122.908 us; speedup vs baseline: 1.4812x; 1.2320x over previous
//
#include <hip/hip_runtime.h>
#include <math.h>

namespace {

constexpr int H = 1024;
constexpr int W = 1024;
constexpr int HW = H * W;
constexpr int TILE = 64;             // output tile edge
constexpr int HALO = 16;             // = steps fused per launch
constexpr int P = 96;                // halo'd tile edge
constexpr int NLAUNCH = 4;           // 4 x 16 = 64 steps
constexpr int NTX = W / TILE;        // 16 tiles per dim
constexpr int NTHREADS = 1024;       // 16 waves = 4/SIMD
constexpr int PITCHF = P + 4;        // 100 floats/row: b128-aligned rows; pad
                                     // legalizes the +4 right-edge read.

typedef float f2 __attribute__((ext_vector_type(2)));
typedef float f4 __attribute__((ext_vector_type(4)));

__device__ __forceinline__ float clampf(float v, float lo, float hi) {
    return fminf(fmaxf(v, lo), hi);           // -> v_med3_f32
}
__device__ __forceinline__ f2 clamp2(f2 v, float lo, float hi) {
    f2 r;
    r.x = fminf(fmaxf(v.x, lo), hi);
    r.y = fminf(fmaxf(v.y, lo), hi);
    return r;
}
__device__ __forceinline__ f2 lo2(f4 q) { return __builtin_shufflevector(q, q, 0, 1); }
__device__ __forceinline__ f2 hi2(f4 q) { return __builtin_shufflevector(q, q, 2, 3); }
__device__ __forceinline__ f4 ld4f(const float* p) {
    return *reinterpret_cast<const f4*>(p);
}
// DPP wave shifts (correctness validated in R12-R14 passing kernels):
// 0x138 (wave_shr:1) -> lane i gets lane i-1's value (left neighbor);
// 0x130 (wave_shl:1) -> lane i gets lane i+1's value (right neighbor).
// bound_ctrl=false: boundary lanes keep their own value.
__device__ __forceinline__ float dpp_left(float x) {
    int r = __builtin_amdgcn_update_dpp(__float_as_int(x), __float_as_int(x),
                                        0x138, 0xF, 0xF, false);
    return __int_as_float(r);
}
__device__ __forceinline__ float dpp_right(float x) {
    int r = __builtin_amdgcn_update_dpp(__float_as_int(x), __float_as_int(x),
                                        0x130, 0xF, 0xF, false);
    return __int_as_float(r);
}

// One Gray-Scott step for a 4-px row segment, both fields, packed 2-wide.
__device__ __forceinline__ void row_step(
    f4 uN, f4 uC, f4 uD, float uL, float uR,
    f4 vN, f4 vC, f4 vD, float vL, float vR,
    float ix2, float iy2, float Du, float Dv, float f, float fk, float dt,
    f4* outU, f4* outV)
{
    const f2 a0u = lo2(uC), a1u = hi2(uC);
    const f2 a0v = lo2(vC), a1v = hi2(vC);
    const f2 n0u = lo2(uN), n1u = hi2(uN);
    const f2 n0v = lo2(vN), n1v = hi2(vN);
    const f2 b0u = lo2(uD), b1u = hi2(uD);
    const f2 b0v = lo2(vD), b1v = hi2(vD);

    const f2 l0u = { uL, a0u.x };
    const f2 mmu = { a0u.y, a1u.x };
    const f2 r1u = { a1u.y, uR };
    const f2 l0v = { vL, a0v.x };
    const f2 mmv = { a0v.y, a1v.x };
    const f2 r1v = { a1v.y, vR };

    const f2 lu0 = clamp2((l0u + mmu - 2.0f * a0u) * ix2
                        + (n0u + b0u - 2.0f * a0u) * iy2, -10.0f, 10.0f);
    const f2 lu1 = clamp2((mmu + r1u - 2.0f * a1u) * ix2
                        + (n1u + b1u - 2.0f * a1u) * iy2, -10.0f, 10.0f);
    const f2 lv0 = clamp2((l0v + mmv - 2.0f * a0v) * ix2
                        + (n0v + b0v - 2.0f * a0v) * iy2, -10.0f, 10.0f);
    const f2 lv1 = clamp2((mmv + r1v - 2.0f * a1v) * ix2
                        + (n1v + b1v - 2.0f * a1v) * iy2, -10.0f, 10.0f);

    const f2 uvv0 = a0u * a0v * a0v;
    const f2 uvv1 = a1u * a1v * a1v;

    const f2 du0 = clamp2(Du * lu0 - uvv0 + f * (1.0f - a0u), -1.0f, 1.0f);
    const f2 du1 = clamp2(Du * lu1 - uvv1 + f * (1.0f - a1u), -1.0f, 1.0f);
    const f2 dv0 = clamp2(Dv * lv0 + uvv0 - fk * a0v, -1.0f, 1.0f);
    const f2 dv1 = clamp2(Dv * lv1 + uvv1 - fk * a1v, -1.0f, 1.0f);

    const f2 ou0 = clamp2(a0u + du0 * dt, 0.0f, 2.0f);
    const f2 ou1 = clamp2(a1u + du1 * dt, 0.0f, 2.0f);
    const f2 ov0 = clamp2(a0v + dv0 * dt, 0.0f, 2.0f);
    const f2 ov1 = clamp2(a1v + dv1 * dt, 0.0f, 2.0f);

    *outU = __builtin_shufflevector(ou0, ou1, 0, 1, 2, 3);
    *outV = __builtin_shufflevector(ov0, ov1, 0, 1, 2, 3);
}

// 16 fused Gray-Scott steps on a 64x64 tile, halo 16 (= R10 structure).
// U,V in separate double-buffered LDS arrays, center reads aligned b128.
// NEW vs R10: L/R edge values come from DPP cross-lane shifts (VALU pipe)
// instead of 8 extra b128 LDS reads; sparse exec-masked b32 LDS fallbacks
// cover (a) row-straddle lanes (j==0 / j==NC-1), (b) wave-edge lanes 0/63.
// The last task of a row always has j==NC-1, so lanes whose DPP source is a
// loop-exited lane are always overridden. c4==0's left edge feeds only
// garbage-ring col 0 -> no read needed. Step s computes rows/cols [s,95-s];
// outside is clamped-finite garbage never read by the valid region.
// Step 16 (exactly the interior) writes straight to global.
__global__ __launch_bounds__(NTHREADS) void gs_tile(
    const float* __restrict__ Uin, const float* __restrict__ Vin,
    float* __restrict__ Uout, float* __restrict__ Vout,
    const float* __restrict__ pLogDu, const float* __restrict__ pLogDv,
    const float* __restrict__ pf, const float* __restrict__ pk,
    float invDX2, float invDY2, float dt)
{
    __shared__ __align__(16) float sU[2][P * PITCHF];   // 2 x 38.4 KB
    __shared__ __align__(16) float sV[2][P * PITCHF];   // total 153.6 KB

    const int tid  = threadIdx.x;
    const int lane = tid & 63;
    const int bx = blockIdx.x & (NTX - 1);
    const int by = blockIdx.x >> 4;
    const int gx0 = bx * TILE - HALO;
    const int gy0 = by * TILE - HALO;

    const float Du = clampf(expf(pLogDu[0]), 0.001f, 1.0f);
    const float Dv = clampf(expf(pLogDv[0]), 0.001f, 1.0f);
    const float f = pf[0], k = pk[0];
    const float fk = f + k;

    // ---- load 96x96 halo'd tile (periodic wrap). No clamps: inputs are in
    // [0,2] by construction, so the reference's leading clip is the identity.
    for (int t = tid; t < P * (P / 4); t += NTHREADS) {   // 2304 4-px strips
        const int r  = t / (P / 4);
        const int c4 = (t - r * (P / 4)) * 4;
        const int gy = (gy0 + r) & (H - 1);
        const int gx = (gx0 + c4) & (W - 1);              // 4-aligned, no mid-vec wrap
        *reinterpret_cast<f4*>(&sU[0][r * PITCHF + c4]) = ld4f(Uin + gy * W + gx);
        *reinterpret_cast<f4*>(&sV[0][r * PITCHF + c4]) = ld4f(Vin + gy * W + gx);
    }
    __syncthreads();

    int b = 0;

#define GS_STEP(S, NC, C4LO)                                                     \
    {                                                                            \
        const float* __restrict__ cU = sU[b];                                    \
        const float* __restrict__ cV = sV[b];                                    \
        float* __restrict__ nU = sU[b ^ 1];                                      \
        float* __restrict__ nV = sV[b ^ 1];                                      \
        const int npair = (P - 2 * (S)) >> 1;                                    \
        const int tasks = npair * (NC);                                          \
        for (int t = tid; t < tasks; t += NTHREADS) {                            \
            const int pr  = t / (NC);                                            \
            const int j   = t - pr * (NC);                                       \
            const int row = (S) + 2 * pr;                                        \
            const int c4  = (C4LO) + j * 4;                                      \
            const int oA  = row * PITCHF + c4;                                   \
            const f4 uN = ld4f(cU + oA - PITCHF);                                \
            const f4 uA = ld4f(cU + oA);                                         \
            const f4 uB = ld4f(cU + oA + PITCHF);                                \
            const f4 uS = ld4f(cU + oA + 2 * PITCHF);                            \
            const f4 vN = ld4f(cV + oA - PITCHF);                                \
            const f4 vA = ld4f(cV + oA);                                         \
            const f4 vB = ld4f(cV + oA + PITCHF);                                \
            const f4 vS = ld4f(cV + oA + 2 * PITCHF);                            \
            float uLa = dpp_left(uA.w), uRa = dpp_right(uA.x);                   \
            float uLb = dpp_left(uB.w), uRb = dpp_right(uB.x);                   \
            float vLa = dpp_left(vA.w), vRa = dpp_right(vA.x);                   \
            float vLb = dpp_left(vB.w), vRb = dpp_right(vB.x);                   \
            if ((lane == 0 || j == 0) && c4 > 0) {                               \
                uLa = cU[oA - 1]; uLb = cU[oA + PITCHF - 1];                     \
                vLa = cV[oA - 1]; vLb = cV[oA + PITCHF - 1];                     \
            }                                                                    \
            if (lane == 63 || j == (NC) - 1) {                                   \
                uRa = cU[oA + 4]; uRb = cU[oA + PITCHF + 4];                     \
                vRa = cV[oA + 4]; vRb = cV[oA + PITCHF + 4];                     \
            }                                                                    \
            f4 ouA, ovA, ouB, ovB;                                               \
            row_step(uN, uA, uB, uLa, uRa, vN, vA, vB, vLa, vRa,                 \
                     invDX2, invDY2, Du, Dv, f, fk, dt, &ouA, &ovA);             \
            row_step(uA, uB, uS, uLb, uRb, vA, vB, vS, vLb, vRb,                 \
                     invDX2, invDY2, Du, Dv, f, fk, dt, &ouB, &ovB);             \
            *reinterpret_cast<f4*>(nU + oA)          = ouA;                      \
            *reinterpret_cast<f4*>(nU + oA + PITCHF) = ouB;                      \
            *reinterpret_cast<f4*>(nV + oA)          = ovA;                      \
            *reinterpret_cast<f4*>(nV + oA + PITCHF) = ovB;                      \
        }                                                                        \
        b ^= 1;                                                                  \
        __syncthreads();                                                         \
    }

    for (int s = 1; s <= 3; ++s)   GS_STEP(s, 24,  0);    // s=1..3
    for (int s = 4; s <= 7; ++s)   GS_STEP(s, 22,  4);    // s=4..7
    for (int s = 8; s <= 11; ++s)  GS_STEP(s, 20,  8);    // s=8..11
    for (int s = 12; s <= 15; ++s) GS_STEP(s, 18, 12);    // s=12..15

    // ---- step 16: region is exactly the interior [16,79]^2 -> write global.
    // NC=16 divides 64: j==0 covers lane 0, j==15 covers lane 63.
    {
        const float* __restrict__ cU = sU[b];
        const float* __restrict__ cV = sV[b];
        if (tid < 32 * 16) {                              // 512 tasks, waves 0-7
            const int pr  = tid / 16;
            const int j   = tid - pr * 16;
            const int row = 16 + 2 * pr;
            const int c4  = 16 + j * 4;
            const int oA  = row * PITCHF + c4;
            const f4 uN = ld4f(cU + oA - PITCHF);
            const f4 uA = ld4f(cU + oA);
            const f4 uB = ld4f(cU + oA + PITCHF);
            const f4 uS = ld4f(cU + oA + 2 * PITCHF);
            const f4 vN = ld4f(cV + oA - PITCHF);
            const f4 vA = ld4f(cV + oA);
            const f4 vB = ld4f(cV + oA + PITCHF);
            const f4 vS = ld4f(cV + oA + 2 * PITCHF);
            float uLa = dpp_left(uA.w), uRa = dpp_right(uA.x);
            float uLb = dpp_left(uB.w), uRb = dpp_right(uB.x);
            float vLa = dpp_left(vA.w), vRa = dpp_right(vA.x);
            float vLb = dpp_left(vB.w), vRb = dpp_right(vB.x);
            if (j == 0) {
                uLa = cU[oA - 1]; uLb = cU[oA + PITCHF - 1];
                vLa = cV[oA - 1]; vLb = cV[oA + PITCHF - 1];
            }
            if (j == 15) {
                uRa = cU[oA + 4]; uRb = cU[oA + PITCHF + 4];
                vRa = cV[oA + 4]; vRb = cV[oA + PITCHF + 4];
            }
            f4 ouA, ovA, ouB, ovB;
            row_step(uN, uA, uB, uLa, uRa, vN, vA, vB, vLa, vRa,
                     invDX2, invDY2, Du, Dv, f, fk, dt, &ouA, &ovA);
            row_step(uA, uB, uS, uLb, uRb, vA, vB, vS, vLb, vRb,
                     invDX2, invDY2, Du, Dv, f, fk, dt, &ouB, &ovB);
            const int go = (by * TILE + row - HALO) * W + bx * TILE + (c4 - HALO);
            *reinterpret_cast<f4*>(Uout + go)     = ouA;
            *reinterpret_cast<f4*>(Uout + go + W) = ouB;
            *reinterpret_cast<f4*>(Vout + go)     = ovA;
            *reinterpret_cast<f4*>(Vout + go + W) = ovB;
        }
    }
#undef GS_STEP
}

} // namespace

extern "C" void kernel_launch(void* const* d_in, const int* in_sizes, int n_in,
                              void* d_out, int out_size, void* d_ws, size_t ws_size,
                              hipStream_t stream) {
    const float* U0     = (const float*)d_in[0];
    const float* V0     = (const float*)d_in[1];
    const float* pLogDu = (const float*)d_in[2];
    const float* pLogDv = (const float*)d_in[3];
    const float* pf     = (const float*)d_in[4];
    const float* pk     = (const float*)d_in[5];
    // d_in[6] = steps (int32) — fixed at 64 by the problem definition.

    float* wsU  = (float*)d_ws;   // 4 MB
    float* wsV  = wsU + HW;       // 4 MB
    float* outU = (float*)d_out;  // output layout: [U (HW) | V (HW)]
    float* outV = outU + HW;

    const double dx  = 1.0 / (W - 1);
    const double dy  = 1.0 / (H - 1);
    const double dx2 = dx * dx;
    const double dy2 = dy * dy;
    const float invdx2 = (float)(1.0 / dx2);
    const float invdy2 = (float)(1.0 / dy2);
    const float dtf    = (float)(0.1 * ((dx2 < dy2) ? dx2 : dy2) / (4.0 * 0.16));

    const int grid = (H / TILE) * (W / TILE);   // 256 blocks = 1 per CU

    // 4 launches of 16 fused steps, ping-pong ws <-> d_out; launch 3 (odd)
    // leaves the final state exactly in d_out.
    const float* cu = U0;
    const float* cv = V0;
    for (int l = 0; l < NLAUNCH; ++l) {
        float* nu;
        float* nv;
        if (l & 1) { nu = outU; nv = outV; }
        else       { nu = wsU;  nv = wsV;  }
        gs_tile<<<grid, NTHREADS, 0, stream>>>(cu, cv, nu, nv,
                                               pLogDu, pLogDv, pf, pk,
                                               invdx2, invdy2, dtf);
        cu = nu; cv = nv;
    }
}